// Round 6
// baseline (218.408 us; speedup 1.0000x reference)
//
#include <hip/hip_runtime.h>
#include <hip/hip_bf16.h>
#include <hip/hip_fp16.h>

#define FEAT 2048
#define NCLS 751
#define NPAD 768
#define NPRB 64
#define NGAL 256
#define WSCALE 256.0f

typedef _Float16 f16x8 __attribute__((ext_vector_type(8)));
typedef float f32x4 __attribute__((ext_vector_type(4)));

__device__ __forceinline__ unsigned short f2h_u(float x) {
  union { _Float16 h; unsigned short u; } v;
  v.h = (_Float16)x;
  return v.u;
}

// ---------------------------------------------------------------------------
// Kernel 1: per-feature moments of probe/gallery -> BN scale s[f], shift t[f]
// mean[f] = E_pg[(p-g)^2] = M2p - 2 M1p M1g + M2g   (exact, cross-product)
// E[d^2]  = M4p - 4 M3p M1g + 6 M2p M2g - 4 M1p M3g + M4g
// (R4-proven version: deterministic, no cross-block state.)
// ---------------------------------------------------------------------------
__global__ void stats_kernel(const float* __restrict__ P, const float* __restrict__ G,
                             const float* __restrict__ gamma, const float* __restrict__ beta,
                             float* __restrict__ st) {
  int fx = threadIdx.x & 31, ry = threadIdx.x >> 5;
  int f = blockIdx.x * 32 + fx;
  float a1 = 0, a2 = 0, a3 = 0, a4 = 0;
  for (int r = ry; r < NPRB; r += 8) {
    float x = P[r * FEAT + f], x2 = x * x;
    a1 += x; a2 += x2; a3 += x2 * x; a4 += x2 * x2;
  }
  float b1 = 0, b2 = 0, b3 = 0, b4 = 0;
  for (int r = ry; r < NGAL; r += 8) {
    float x = G[r * FEAT + f], x2 = x * x;
    b1 += x; b2 += x2; b3 += x2 * x; b4 += x2 * x2;
  }
  __shared__ float red[8][8][32];
  float vals[8] = {a1, a2, a3, a4, b1, b2, b3, b4};
#pragma unroll
  for (int m = 0; m < 8; ++m) red[m][ry][fx] = vals[m];
  __syncthreads();
  if (ry == 0) {
    float mm[8];
#pragma unroll
    for (int m = 0; m < 8; ++m) {
      float sum = 0.f;
#pragma unroll
      for (int r = 0; r < 8; ++r) sum += red[m][r][fx];
      mm[m] = sum;
    }
    float M1p = mm[0] * (1.f / NPRB), M2p = mm[1] * (1.f / NPRB);
    float M3p = mm[2] * (1.f / NPRB), M4p = mm[3] * (1.f / NPRB);
    float M1g = mm[4] * (1.f / NGAL), M2g = mm[5] * (1.f / NGAL);
    float M3g = mm[6] * (1.f / NGAL), M4g = mm[7] * (1.f / NGAL);
    float mean = M2p - 2.f * M1p * M1g + M2g;
    float Ed2 = M4p - 4.f * M3p * M1g + 6.f * M2p * M2g - 4.f * M1p * M3g + M4g;
    float var = Ed2 - mean * mean;
    float sv = gamma[f] / sqrtf(var + 1e-5f);
    st[f] = sv;
    st[FEAT + f] = beta[f] - mean * sv;  // t[f]
  }
}

// ---------------------------------------------------------------------------
// Kernel 2 (R4-proven): W -> MFMA-fragment-ordered Wf + deterministic bias.
// Wf layout: [nblk=c/16][kc=f/8][row=c%16][8 f16], value W*s*WSCALE.
// One block per 16-class group (48 blocks); bp written exactly once,
// no atomics, no memset dependency.
// ---------------------------------------------------------------------------
__global__ void prepw_kernel(const float* __restrict__ W, const float* __restrict__ b,
                             const float* __restrict__ st,
                             unsigned short* __restrict__ Wf, float* __restrict__ bp) {
  const int nblk = blockIdx.x;       // 0..47
  const int t = threadIdx.x;
  const int row = t & 15;            // class within group
  const int c = nblk * 16 + row;
  const int kcb = t >> 4;            // 0..15
  unsigned short* wbase = Wf + (size_t)nblk * 32768;
  float part = 0.f;
#pragma unroll 4
  for (int i = 0; i < 16; ++i) {
    int kc = i * 16 + kcb;
    int f = kc * 8;
    float4 w0 = make_float4(0.f, 0.f, 0.f, 0.f), w1 = w0;
    if (c < NCLS) {
      const float4* ws = (const float4*)(W + (size_t)c * FEAT + f);
      w0 = ws[0]; w1 = ws[1];
    }
    const float4* s4 = (const float4*)(st + f);
    float4 s0 = s4[0], s1 = s4[1];
    const float4* t4 = (const float4*)(st + FEAT + f);
    float4 t0 = t4[0], t1 = t4[1];
    uint4 u;
    u.x = (unsigned int)f2h_u(w0.x * s0.x * WSCALE) | ((unsigned int)f2h_u(w0.y * s0.y * WSCALE) << 16);
    u.y = (unsigned int)f2h_u(w0.z * s0.z * WSCALE) | ((unsigned int)f2h_u(w0.w * s0.w * WSCALE) << 16);
    u.z = (unsigned int)f2h_u(w1.x * s1.x * WSCALE) | ((unsigned int)f2h_u(w1.y * s1.y * WSCALE) << 16);
    u.w = (unsigned int)f2h_u(w1.z * s1.z * WSCALE) | ((unsigned int)f2h_u(w1.w * s1.w * WSCALE) << 16);
    *(uint4*)(wbase + (size_t)kc * 128 + row * 8) = u;
    part += t0.x * w0.x + t0.y * w0.y + t0.z * w0.z + t0.w * w0.w +
            t1.x * w1.x + t1.y * w1.y + t1.z * w1.z + t1.w * w1.w;
  }
  __shared__ float red[16][16];  // [kcb][row]
  red[kcb][row] = part;
  __syncthreads();
  if (t < 16) {
    float sum = (nblk * 16 + t < NCLS) ? b[nblk * 16 + t] : 0.f;
#pragma unroll
    for (int j = 0; j < 16; ++j) sum += red[j][t];
    bp[nblk * 16 + t] = sum;
  }
}

// ---------------------------------------------------------------------------
// Kernel 3: A'[n,f] = (P[p,f]-G[g,f])^2 as f16 in MFMA fragment order:
// A'[mblk=n/16][kc=f/8][row=n%16][8].  One block per mblk (1024 blocks).
// ---------------------------------------------------------------------------
__global__ void agen_kernel(const float* __restrict__ P, const float* __restrict__ G,
                            unsigned short* __restrict__ A) {
  const int mblk = blockIdx.x;
  const int row = threadIdx.x & 15, kcb = threadIdx.x >> 4;
  const int p = mblk >> 4;
  const int g = (mblk & 15) * 16 + row;
  unsigned short* abase = A + (size_t)mblk * 32768;
#pragma unroll 4
  for (int i = 0; i < 16; ++i) {
    int kc = i * 16 + kcb;
    int f = kc * 8;
    const float4* p4 = (const float4*)(P + (size_t)p * FEAT + f);
    const float4* g4 = (const float4*)(G + (size_t)g * FEAT + f);
    float4 pa = p4[0], pb = p4[1];
    float4 ga = g4[0], gb = g4[1];
    float d0 = pa.x - ga.x, d1 = pa.y - ga.y, d2 = pa.z - ga.z, d3 = pa.w - ga.w;
    float d4 = pb.x - gb.x, d5 = pb.y - gb.y, d6 = pb.z - gb.z, d7 = pb.w - gb.w;
    uint4 u;
    u.x = (unsigned int)f2h_u(d0 * d0) | ((unsigned int)f2h_u(d1 * d1) << 16);
    u.y = (unsigned int)f2h_u(d2 * d2) | ((unsigned int)f2h_u(d3 * d3) << 16);
    u.z = (unsigned int)f2h_u(d4 * d4) | ((unsigned int)f2h_u(d5 * d5) << 16);
    u.w = (unsigned int)f2h_u(d6 * d6) | ((unsigned int)f2h_u(d7 * d7) << 16);
    *(uint4*)(abase + (size_t)kc * 128 + row * 8) = u;
  }
}

// ---------------------------------------------------------------------------
// Kernel 4: f16 GEMM with ZERO LDS. Both A' and Wf are in fragment order, so
// each wave loads its fragments as contiguous 1 KB global_load_dwordx4
// (base + lane*16B). No barriers; register ping-pong double-buffer at BK=32.
// 128x128 block tile, 4 waves of 64x64 (4x4 x 16x16x32 MFMA).
// ---------------------------------------------------------------------------
__global__ __launch_bounds__(256, 3)
void gemm_kernel(const unsigned short* __restrict__ A,
                 const unsigned short* __restrict__ Wf,
                 const float* __restrict__ bp, float* __restrict__ out) {
  const int tid = threadIdx.x;
  const int lane = tid & 63, wave = tid >> 6;
  const int ntile = blockIdx.x, mtile = blockIdx.y;
  const int wm = (wave & 1) * 64, wn = (wave >> 1) * 64;

  // fragment bases: frag(mi, k0) = ab + mi*32768 + k0*16  (elems)
  const unsigned short* ab = A + ((size_t)mtile * 8 + (wm >> 4)) * 32768 + lane * 8;
  const unsigned short* bb = Wf + ((size_t)ntile * 8 + (wn >> 4)) * 32768 + lane * 8;

  f32x4 acc[4][4];
#pragma unroll
  for (int mi = 0; mi < 4; ++mi)
#pragma unroll
    for (int ni = 0; ni < 4; ++ni) acc[mi][ni] = (f32x4){0.f, 0.f, 0.f, 0.f};

  f16x8 afa[4], bfa[4], afb[4], bfb[4];

#define LD_A(DST, K0)                                                      \
  _Pragma("unroll") for (int mi = 0; mi < 4; ++mi)                         \
      DST[mi] = *(const f16x8*)(ab + (size_t)mi * 32768 + (K0) * 16);
#define LD_B(DST, K0)                                                      \
  _Pragma("unroll") for (int ni = 0; ni < 4; ++ni)                         \
      DST[ni] = *(const f16x8*)(bb + (size_t)ni * 32768 + (K0) * 16);
#define MM(AF, BF)                                                         \
  _Pragma("unroll") for (int mi = 0; mi < 4; ++mi)                         \
    _Pragma("unroll") for (int ni = 0; ni < 4; ++ni)                       \
        acc[mi][ni] = __builtin_amdgcn_mfma_f32_16x16x32_f16(              \
            AF[mi], BF[ni], acc[mi][ni], 0, 0, 0);

  LD_A(afa, 0) LD_B(bfa, 0)
  for (int k0 = 0; k0 < FEAT; k0 += 64) {
    LD_A(afb, k0 + 32) LD_B(bfb, k0 + 32)
    MM(afa, bfa)
    if (k0 + 64 < FEAT) { LD_A(afa, k0 + 64) LD_B(bfa, k0 + 64) }
    MM(afb, bfb)
  }
#undef LD_A
#undef LD_B
#undef MM

  // epilogue: C/D layout col=lane&15, row=(lane>>4)*4+reg; undo WSCALE, add b'
  const int col0 = ntile * 128 + wn + (lane & 15);
  const int row0 = mtile * 128 + wm + ((lane >> 4) << 2);
#pragma unroll
  for (int ni = 0; ni < 4; ++ni) {
    int col = col0 + ni * 16;
    if (col >= NCLS) continue;
    float bv = bp[col];
#pragma unroll
    for (int mi = 0; mi < 4; ++mi) {
      int row = row0 + mi * 16;
#pragma unroll
      for (int r = 0; r < 4; ++r)
        out[(size_t)(row + r) * NCLS + col] = acc[mi][ni][r] * (1.0f / WSCALE) + bv;
    }
  }
}

// ---------------------------------------------------------------------------
extern "C" void kernel_launch(void* const* d_in, const int* in_sizes, int n_in,
                              void* d_out, int out_size, void* d_ws, size_t ws_size,
                              hipStream_t stream) {
  const float* P = (const float*)d_in[0];
  const float* G = (const float*)d_in[1];
  const float* gamma = (const float*)d_in[2];
  const float* beta = (const float*)d_in[3];
  const float* W = (const float*)d_in[4];
  const float* b = (const float*)d_in[5];
  float* out = (float*)d_out;

  float* st = (float*)d_ws;                           // s[2048], t[2048]
  float* bp = st + 2 * FEAT;                          // b'[768]
  unsigned short* Wf = (unsigned short*)(bp + NPAD);  // f16 Wf [48*32768]
  unsigned short* A = Wf + (size_t)48 * 32768;        // f16 A' [1024*32768]

  hipLaunchKernelGGL(agen_kernel, dim3(1024), dim3(256), 0, stream, P, G, A);
  hipLaunchKernelGGL(stats_kernel, dim3(64), dim3(256), 0, stream, P, G, gamma, beta, st);
  hipLaunchKernelGGL(prepw_kernel, dim3(48), dim3(256), 0, stream, W, b, st, Wf, bp);
  hipLaunchKernelGGL(gemm_kernel, dim3(6, 128), dim3(256), 0, stream, A, Wf, bp, out);
}

// Round 8
// 176.889 us; speedup vs baseline: 1.2347x; 1.2347x over previous
//
#include <hip/hip_runtime.h>
#include <hip/hip_bf16.h>
#include <hip/hip_fp16.h>

#define FEAT 2048
#define NCLS 751
#define NPAD 768
#define NPRB 64
#define NGAL 256
#define WSCALE 256.0f

typedef _Float16 f16x8 __attribute__((ext_vector_type(8)));
typedef float f32x4 __attribute__((ext_vector_type(4)));

__device__ __forceinline__ unsigned short f2h_u(float x) {
  union { _Float16 h; unsigned short u; } v;
  v.h = (_Float16)x;
  return v.u;
}

// ---------------------------------------------------------------------------
// agen body (R3-proven): A[n,f] = (P[p,f]-G[g,f])^2 f16 row-major, one row
// per iteration, 256 threads x 8 elems.
// ---------------------------------------------------------------------------
__device__ __forceinline__ void agen_row(const float* __restrict__ P,
                                         const float* __restrict__ G,
                                         unsigned short* __restrict__ A,
                                         int n, int tid) {
  int p = n >> 8, g = n & 255;
  int f = tid * 8;
  const float4* p4 = (const float4*)(P + (size_t)p * FEAT + f);
  const float4* g4 = (const float4*)(G + (size_t)g * FEAT + f);
  float4 pa = p4[0], pb = p4[1];
  float4 ga = g4[0], gb = g4[1];
  float d0 = pa.x - ga.x, d1 = pa.y - ga.y, d2 = pa.z - ga.z, d3 = pa.w - ga.w;
  float d4 = pb.x - gb.x, d5 = pb.y - gb.y, d6 = pb.z - gb.z, d7 = pb.w - gb.w;
  uint4 u;
  u.x = (unsigned int)f2h_u(d0 * d0) | ((unsigned int)f2h_u(d1 * d1) << 16);
  u.y = (unsigned int)f2h_u(d2 * d2) | ((unsigned int)f2h_u(d3 * d3) << 16);
  u.z = (unsigned int)f2h_u(d4 * d4) | ((unsigned int)f2h_u(d5 * d5) << 16);
  u.w = (unsigned int)f2h_u(d6 * d6) | ((unsigned int)f2h_u(d7 * d7) << 16);
  *(uint4*)(A + (size_t)n * FEAT + f) = u;
}

// ---------------------------------------------------------------------------
// Kernel 1: blocks 0..63 = stats (R3-proven body); blocks 64..575 = agen
// rows 0..8191 (grid-stride). Independent work, no cross-block deps.
// ---------------------------------------------------------------------------
__global__ void k1_stats_agen(const float* __restrict__ P, const float* __restrict__ G,
                              const float* __restrict__ gamma, const float* __restrict__ beta,
                              float* __restrict__ st, unsigned short* __restrict__ A) {
  const int blk = blockIdx.x, tid = threadIdx.x;
  if (blk < 64) {
    __shared__ float red[8][8][32];
    int fx = tid & 31, ry = tid >> 5;
    int f = blk * 32 + fx;
    float a1 = 0, a2 = 0, a3 = 0, a4 = 0;
    for (int r = ry; r < NPRB; r += 8) {
      float x = P[r * FEAT + f], x2 = x * x;
      a1 += x; a2 += x2; a3 += x2 * x; a4 += x2 * x2;
    }
    float b1 = 0, b2 = 0, b3 = 0, b4 = 0;
    for (int r = ry; r < NGAL; r += 8) {
      float x = G[r * FEAT + f], x2 = x * x;
      b1 += x; b2 += x2; b3 += x2 * x; b4 += x2 * x2;
    }
    float vals[8] = {a1, a2, a3, a4, b1, b2, b3, b4};
#pragma unroll
    for (int m = 0; m < 8; ++m) red[m][ry][fx] = vals[m];
    __syncthreads();
    if (ry == 0) {
      float mm[8];
#pragma unroll
      for (int m = 0; m < 8; ++m) {
        float sum = 0.f;
#pragma unroll
        for (int r = 0; r < 8; ++r) sum += red[m][r][fx];
        mm[m] = sum;
      }
      float M1p = mm[0] * (1.f / NPRB), M2p = mm[1] * (1.f / NPRB);
      float M3p = mm[2] * (1.f / NPRB), M4p = mm[3] * (1.f / NPRB);
      float M1g = mm[4] * (1.f / NGAL), M2g = mm[5] * (1.f / NGAL);
      float M3g = mm[6] * (1.f / NGAL), M4g = mm[7] * (1.f / NGAL);
      float mean = M2p - 2.f * M1p * M1g + M2g;
      float Ed2 = M4p - 4.f * M3p * M1g + 6.f * M2p * M2g - 4.f * M1p * M3g + M4g;
      float var = Ed2 - mean * mean;
      float sv = gamma[f] / sqrtf(var + 1e-5f);
      st[f] = sv;
      st[FEAT + f] = beta[f] - mean * sv;  // t[f]
    }
  } else {
    for (int n = blk - 64; n < 8192; n += 512) agen_row(P, G, A, n, tid);
  }
}

// ---------------------------------------------------------------------------
// Kernel 2: blocks 0..47 = prepw (R3-proven body: W' row-major f16 + bias,
// deterministic in-block reduction); blocks 48..559 = agen rows 8192..16383.
// ---------------------------------------------------------------------------
__global__ void k2_prepw_agen(const float* __restrict__ P, const float* __restrict__ G,
                              const float* __restrict__ W, const float* __restrict__ b,
                              const float* __restrict__ st,
                              unsigned short* __restrict__ Wp, float* __restrict__ bp,
                              unsigned short* __restrict__ A) {
  const int blk = blockIdx.x, t = threadIdx.x;
  if (blk < 48) {
    const int nblk = blk;
    const int row = t & 15;            // class within group
    const int c = nblk * 16 + row;
    const int kcb = t >> 4;            // 0..15
    float part = 0.f;
#pragma unroll 4
    for (int i = 0; i < 16; ++i) {
      int kc = i * 16 + kcb;
      int f = kc * 8;
      float4 w0 = make_float4(0.f, 0.f, 0.f, 0.f), w1 = w0;
      if (c < NCLS) {
        const float4* ws = (const float4*)(W + (size_t)c * FEAT + f);
        w0 = ws[0]; w1 = ws[1];
      }
      const float4* s4 = (const float4*)(st + f);
      float4 s0 = s4[0], s1 = s4[1];
      const float4* t4 = (const float4*)(st + FEAT + f);
      float4 t0 = t4[0], t1 = t4[1];
      uint4 u;
      u.x = (unsigned int)f2h_u(w0.x * s0.x * WSCALE) | ((unsigned int)f2h_u(w0.y * s0.y * WSCALE) << 16);
      u.y = (unsigned int)f2h_u(w0.z * s0.z * WSCALE) | ((unsigned int)f2h_u(w0.w * s0.w * WSCALE) << 16);
      u.z = (unsigned int)f2h_u(w1.x * s1.x * WSCALE) | ((unsigned int)f2h_u(w1.y * s1.y * WSCALE) << 16);
      u.w = (unsigned int)f2h_u(w1.z * s1.z * WSCALE) | ((unsigned int)f2h_u(w1.w * s1.w * WSCALE) << 16);
      // W' row-major [c][f], 8 f16 per thread-chunk
      *(uint4*)(Wp + (size_t)c * FEAT + f) = u;
      part += t0.x * w0.x + t0.y * w0.y + t0.z * w0.z + t0.w * w0.w +
              t1.x * w1.x + t1.y * w1.y + t1.z * w1.z + t1.w * w1.w;
    }
    __shared__ float red[16][16];  // [kcb][row]
    red[kcb][row] = part;
    __syncthreads();
    if (t < 16) {
      float sum = (nblk * 16 + t < NCLS) ? b[nblk * 16 + t] : 0.f;
#pragma unroll
      for (int j = 0; j < 16; ++j) sum += red[j][t];
      bp[nblk * 16 + t] = sum;
    }
  } else {
    for (int n = 8192 + (blk - 48); n < NPRB * NGAL; n += 512) agen_row(P, G, A, n, t);
  }
}

// ---------------------------------------------------------------------------
// Kernel 3: R3-proven f16 GEMM. M=16384, N=768, K=2048. BK=64, XOR-swizzled
// LDS (conflict-free b128 reads), global_load_lds width-16 staging.
// ---------------------------------------------------------------------------
__global__ __launch_bounds__(256, 3)
void gemm_kernel(const unsigned short* __restrict__ A,
                 const unsigned short* __restrict__ Wp,
                 const float* __restrict__ bp, float* __restrict__ out) {
  __shared__ unsigned short As[128 * 64];  // 16 KB
  __shared__ unsigned short Bs[128 * 64];  // 16 KB

  const int tid = threadIdx.x;
  const int lane = tid & 63, wave = tid >> 6;
  const int mtile = blockIdx.x, ntile = blockIdx.y;

  const int srow = tid >> 3;                     // 0..31
  const int sch = (tid & 7) ^ (srow & 7);        // swizzled source chunk
  const unsigned short* ag = A + (size_t)(mtile * 128 + srow) * FEAT + sch * 8;
  const unsigned short* bg = Wp + (size_t)(ntile * 128 + srow) * FEAT + sch * 8;
  char* alds = (char*)As + wave * 1024;  // wave-uniform; HW adds lane*16
  char* blds = (char*)Bs + wave * 1024;

  f32x4 acc[4][4];
#pragma unroll
  for (int mi = 0; mi < 4; ++mi)
#pragma unroll
    for (int ni = 0; ni < 4; ++ni) acc[mi][ni] = (f32x4){0.f, 0.f, 0.f, 0.f};

  const int wm = (wave & 1) * 64, wn = (wave >> 1) * 64;
  const int frow = lane & 15, fsw = lane & 7, fk = lane >> 4;

  for (int k0 = 0; k0 < FEAT; k0 += 64) {
    __syncthreads();
#pragma unroll
    for (int j = 0; j < 4; ++j) {
      __builtin_amdgcn_global_load_lds(
          (const __attribute__((address_space(1))) void*)(ag + k0 + (size_t)j * 32 * FEAT),
          (__attribute__((address_space(3))) void*)(alds + j * 4096), 16, 0, 0);
      __builtin_amdgcn_global_load_lds(
          (const __attribute__((address_space(1))) void*)(bg + k0 + (size_t)j * 32 * FEAT),
          (__attribute__((address_space(3))) void*)(blds + j * 4096), 16, 0, 0);
    }
    __syncthreads();  // vmcnt(0) drained here: tiles valid

#pragma unroll
    for (int kk = 0; kk < 2; ++kk) {
      const int slot = (kk * 4 + fk) ^ fsw;  // LDS slot holding k-chunk kk*4+fk
      f16x8 af[4], bf[4];
#pragma unroll
      for (int mi = 0; mi < 4; ++mi)
        af[mi] = *(const f16x8*)(As + (wm + mi * 16 + frow) * 64 + slot * 8);
#pragma unroll
      for (int ni = 0; ni < 4; ++ni)
        bf[ni] = *(const f16x8*)(Bs + (wn + ni * 16 + frow) * 64 + slot * 8);
#pragma unroll
      for (int mi = 0; mi < 4; ++mi)
#pragma unroll
        for (int ni = 0; ni < 4; ++ni)
          acc[mi][ni] = __builtin_amdgcn_mfma_f32_16x16x32_f16(af[mi], bf[ni], acc[mi][ni], 0, 0, 0);
    }
  }

  // epilogue: C/D layout col=lane&15, row=(lane>>4)*4+reg; undo WSCALE, add b'
  const int col0 = ntile * 128 + wn + (lane & 15);
  const int row0 = mtile * 128 + wm + ((lane >> 4) << 2);
#pragma unroll
  for (int ni = 0; ni < 4; ++ni) {
    int col = col0 + ni * 16;
    if (col >= NCLS) continue;
    float bv = bp[col];
#pragma unroll
    for (int mi = 0; mi < 4; ++mi) {
      int row = row0 + mi * 16;
#pragma unroll
      for (int r = 0; r < 4; ++r)
        out[(size_t)(row + r) * NCLS + col] = acc[mi][ni][r] * (1.0f / WSCALE) + bv;
    }
  }
}

// ---------------------------------------------------------------------------
extern "C" void kernel_launch(void* const* d_in, const int* in_sizes, int n_in,
                              void* d_out, int out_size, void* d_ws, size_t ws_size,
                              hipStream_t stream) {
  const float* P = (const float*)d_in[0];
  const float* G = (const float*)d_in[1];
  const float* gamma = (const float*)d_in[2];
  const float* beta = (const float*)d_in[3];
  const float* W = (const float*)d_in[4];
  const float* b = (const float*)d_in[5];
  float* out = (float*)d_out;

  float* st = (float*)d_ws;                           // s[2048], t[2048]
  float* bp = st + 2 * FEAT;                          // b'[768]
  unsigned short* Wp = (unsigned short*)(bp + NPAD);  // f16 W' [768, 2048] row-major
  unsigned short* A = Wp + (size_t)NPAD * FEAT;       // f16 A [16384, 2048] row-major

  hipLaunchKernelGGL(k1_stats_agen, dim3(576), dim3(256), 0, stream, P, G, gamma, beta, st, A);
  hipLaunchKernelGGL(k2_prepw_agen, dim3(560), dim3(256), 0, stream, P, G, W, b, st, Wp, bp, A);
  hipLaunchKernelGGL(gemm_kernel, dim3(128, 6), dim3(256), 0, stream, A, Wp, bp, out);
}